// Round 4
// baseline (2365.684 us; speedup 1.0000x reference)
//
#include <hip/hip_runtime.h>
#include <stdint.h>

#define B_  64
#define T_  1000
#define DI_ 128
#define DR_ 512
#define DO_ 64

// ---------- bf16 helpers ----------
static __device__ __forceinline__ float bfu(uint16_t u){
  union{uint32_t i; float f;} v; v.i = ((uint32_t)u) << 16; return v.f;
}
static __device__ __forceinline__ uint16_t f2bf(float f){
  union{float f; uint32_t i;} v; v.f = f;
  uint32_t i = v.i;
  return (uint16_t)((i + 0x7FFFu + ((i >> 16) & 1u)) >> 16);   // RNE
}

// ---------- dtype-generic scalar IO ----------
template<int BF16> struct IO;
template<> struct IO<1> {
  static __device__ __forceinline__ float ld(const void* p, size_t i){ return bfu(((const uint16_t*)p)[i]); }
  static __device__ __forceinline__ void  st(void* p, size_t i, float v){ ((uint16_t*)p)[i] = f2bf(v); }
};
template<> struct IO<0> {
  static __device__ __forceinline__ float ld(const void* p, size_t i){ return ((const float*)p)[i]; }
  static __device__ __forceinline__ void  st(void* p, size_t i, float v){ ((float*)p)[i] = v; }
};

static __device__ __forceinline__ float retanh_f(float x){
  if (x <= 0.f) return 0.f;
  float e = __expf(2.f * x);
  return 1.f - 2.f / (e + 1.f);
}

// Atomic OR-with-0 returning old value. Atomics bypass L1; without sc1 they
// execute at the XCD L2 atomic point. "=&v" early-clobber: dst must not alias
// the zero operand. (R3-proven delivery mechanism.)
static __device__ __forceinline__ unsigned long long poll_l2_u64(const unsigned long long* p){
  unsigned long long v, z = 0ull;
  asm volatile("global_atomic_or_x2 %0, %1, %2, off sc0\n\t"
               "s_waitcnt vmcnt(0)"
               : "=&v"(v) : "v"(p), "v"(z) : "memory");
  return v;
}

// Publish a packet via atomic swap (no sc1, no return). Fire-and-forget.
static __device__ __forceinline__ void pub_l2_u64(unsigned long long* p, unsigned long long pkt){
  asm volatile("global_atomic_swap_x2 %0, %1, off"
               :: "v"(p), "v"(pkt) : "memory");
}

// Raw barrier with LDS-only drain: ds ops are ordered (lgkmcnt(0)) but vmem
// loads/stores stay in flight across the barrier — removing the ~700-1100cy
// per-step vmcnt(0) drain that __syncthreads() imposes (R3 post-mortem).
// Correctness: all cross-wave data inside the block moves through LDS only;
// cross-block data is tag-validated, so vmem completion order is irrelevant.
static __device__ __forceinline__ void bar_lds(){
  asm volatile("s_waitcnt lgkmcnt(0)" ::: "memory");
  __builtin_amdgcn_sched_barrier(0);
  __builtin_amdgcn_s_barrier();
  __builtin_amdgcn_sched_barrier(0);
}

// ---------- init: dtype detect + zero sync state + per-launch nonce ----------
// Kernel-boundary cache writeback/invalidate makes these plain stores visible
// to the next dispatch. Nonce salts tags so stale packets from any previous
// launch can never satisfy a poll.
__global__ void init_kernel(const uint16_t* __restrict__ bx, int* __restrict__ flag,
                            unsigned* __restrict__ nonce,
                            unsigned* __restrict__ det,
                            unsigned long long* __restrict__ probe,
                            unsigned long long* __restrict__ rglobA){
  size_t i = (size_t)blockIdx.x * blockDim.x + threadIdx.x;
  const size_t n = (size_t)2 * B_ * DR_;     // per-copy slots
  if (i < n) { rglobA[i] = 0ull; rglobA[i + n] = 0ull; }
  if (i < 256) { det[i] = 0u; probe[i] = 0ull; }
  if (i == 0) {
    int small = 0;
    for (int k = 0; k < 24; ++k) {
      uint16_t u = bx[2 * k];
      uint16_t e = (u >> 7) & 0xFF;
      small += (e <= 124) ? 1 : 0;
    }
    *flag = (small == 24) ? 1 : 0;
    unsigned long long rt = __builtin_amdgcn_s_memrealtime();
    __hip_atomic_store(nonce, (((unsigned)(rt >> 4)) & 0x3FFFFFu) | 1u,
                       __ATOMIC_RELAXED, __HIP_MEMORY_SCOPE_AGENT);
  }
}

// ---------- recurrent scan ----------
// 256 blocks = 64 batches x 4 unit-slices of 128 rows. Thread (q, rl):
// q = tid>>7 (col quarter, wave-uniform), rl = tid&127. Wrr slice rows in
// registers (128 f32/thread). r state via LDS.
//
// Cross-slice exchange: tagged 8B packets {tag = (nonce<<10)|(t+1), f32 bits},
// double-buffered by t&1.
//   FAST (probe-verified): atomic swap publish + atomic-or(0) poll, no sc1 —
//     the R3-proven delivery path, now WITHOUT the per-step MALL store.
//   SLOW: R1's agent-scope store + load poll at the coherence point.
// Mode chosen once per batch by an EMPIRICAL probe of the fast mechanism
// itself (nonce-keyed packets), with verdicts exchanged via the MALL path —
// all 4 slices agree; no reliance on dispatch placement or hwreg semantics.
// Overwrite safety (slot parity reuse at t/t+2): publish(t) completes before
// brv(t+1)'s data-dependent vmcnt wait, which precedes publish(t+2); and the
// exchange protocol gates any block from reaching t+2 before every sibling
// consumed step t.
template<int BF16>
__global__ __launch_bounds__(512)
void rnn_run(const void* __restrict__ inp,   // [B,T,DI]
             const void* __restrict__ br,    // [B,T,DR]
             const void* __restrict__ Wrx,   // [DR,DI]
             const void* __restrict__ bx,    // [DR]
             const void* __restrict__ Wrr,   // [DR,DR]
             const void* __restrict__ r0,    // [DR]
             void* __restrict__ rstore,      // [B,T,DR]
             const int* __restrict__ flag,
             const unsigned* __restrict__ nonce_p,
             unsigned* __restrict__ det,               // [B*4] verdicts
             unsigned long long* __restrict__ probe,   // [B*4] fast-path probe
             unsigned long long* __restrict__ rglobA,  // [2][B][DR] MALL copy
             unsigned long long* __restrict__ rglobB)  // [2][B][DR] L2 copy
{
  if (*flag != BF16) return;
  const int blk = blockIdx.x;
  const int b   = blk & 63;
  const int s   = blk >> 6;          // slice 0..3
  const int tid = threadIdx.x;
  const int q   = tid >> 7;          // col quarter 0..3 (wave-uniform)
  const int rl  = tid & 127;         // local row 0..127
  const int row = s * 128 + rl;      // global unit index this thread serves

  __shared__ __align__(16) float s_r[DR_];
  __shared__ __align__(16) float s_in[DI_];
  __shared__ __align__(16) float s_part[DR_];   // [rl*4 + q]
  __shared__ unsigned s_nonce;
  __shared__ int s_fast;

  // ---- weights in registers ----
  float w[128];
  #pragma unroll
  for (int k = 0; k < 128; ++k)
    w[k] = IO<BF16>::ld(Wrr, (size_t)row * DR_ + q * 128 + k);
  float wx[32];
  #pragma unroll
  for (int k = 0; k < 32; ++k)
    wx[k] = IO<BF16>::ld(Wrx, (size_t)row * DI_ + q * 32 + k);

  const float bxj = (q == 0) ? IO<BF16>::ld(bx, row) : 0.f;
  float rj        = (q == 0) ? IO<BF16>::ld(r0, row) : 0.f;

  s_r[tid & 511] = IO<BF16>::ld(r0, tid & 511);     // full r(-1) = r0
  if (tid < DI_) s_in[tid] = IO<BF16>::ld(inp, (size_t)b * T_ * DI_ + tid);

  // ---- empirical fast-path detection (tid 0) ----
  if (tid == 0) {
    const unsigned nr = __hip_atomic_load(nonce_p, __ATOMIC_RELAXED,
                                          __HIP_MEMORY_SCOPE_AGENT);
    const unsigned long long MAGIC =
        ((unsigned long long)nr << 32) | 0xD00DFEEDull;
    pub_l2_u64(&probe[b * 4 + s], MAGIC);
    unsigned got = 0; const unsigned all = 0xFu & ~(1u << s);
    int w2 = 20000;
    while (got != all && w2--) {
      #pragma unroll
      for (int i = 0; i < 4; ++i)
        if (i != s && !(got & (1u << i)))
          if (poll_l2_u64(&probe[b * 4 + i]) == MAGIC) got |= 1u << i;
    }
    __hip_atomic_store(&det[b * 4 + s], (got == all) ? 3u : 1u,
                       __ATOMIC_RELAXED, __HIP_MEMORY_SCOPE_AGENT);
    unsigned fastv = 1u;
    for (int i = 0; i < 4; ++i) {
      unsigned u; long spins = 4000000;
      while ((u = __hip_atomic_load(&det[b * 4 + i], __ATOMIC_RELAXED,
                                    __HIP_MEMORY_SCOPE_AGENT)) == 0u) {
        __builtin_amdgcn_s_sleep(2);
        if (--spins == 0) { u = 1u; break; }
      }
      fastv &= (u == 3u) ? 1u : 0u;
    }
    s_fast  = (int)fastv;
    s_nonce = nr;
  }

  // reader mapping: threads 128..511 (waves 2..7) pull the 384 remote rows
  const int j = tid - 128;
  const int g = j + ((j >= s * 128) ? 128 : 0);

  const size_t base_in = (size_t)b * T_ * DI_;
  const size_t base_r  = (size_t)b * T_ * DR_;
  const size_t ex_base = (size_t)b * DR_;
  bool ok = true;                   // poll timeout guard (never trips co-resident)

  // ---- prefetch one full step ahead so q0's update never waits on HBM ----
  float brv_c = 0.f, inv_c = 0.f;
  if (q == 0) {
    brv_c = IO<BF16>::ld(br, base_r + row);                   // br(0)
    if (T_ > 1) inv_c = IO<BF16>::ld(inp, base_in + DI_ + rl); // inp(1)
  }
  __syncthreads();
  const unsigned nonce = s_nonce;
  const bool     fastp = (s_fast != 0);

  #pragma unroll 1
  for (int t = 0; t < T_; ++t) {
    // issue NEXT-step loads now; consumed next iteration (full-step latency)
    float brv_n = 0.f, inv_n = 0.f;
    if (q == 0 && t + 1 < T_) {
      brv_n = IO<BF16>::ld(br, base_r + (size_t)(t + 1) * DR_ + row);
      if (t + 2 < T_)
        inv_n = IO<BF16>::ld(inp, base_in + (size_t)(t + 2) * DI_ + rl);
    }

    // ---- partial dot: cols q*128.. of Wrr row, q*32.. of Wrx row ----
    float a0 = 0.f, a1 = 0.f, a2 = 0.f, a3 = 0.f;
    const float* rq = s_r + q * 128;
    #pragma unroll
    for (int k = 0; k < 128; k += 4) {
      float4 rv = *(const float4*)(rq + k);          // wave-uniform -> broadcast
      a0 = fmaf(w[k + 0], rv.x, a0);
      a1 = fmaf(w[k + 1], rv.y, a1);
      a2 = fmaf(w[k + 2], rv.z, a2);
      a3 = fmaf(w[k + 3], rv.w, a3);
    }
    const float* iq = s_in + q * 32;
    #pragma unroll
    for (int k = 0; k < 32; k += 4) {
      float4 iv = *(const float4*)(iq + k);
      a0 = fmaf(wx[k + 0], iv.x, a0);
      a1 = fmaf(wx[k + 1], iv.y, a1);
      a2 = fmaf(wx[k + 2], iv.z, a2);
      a3 = fmaf(wx[k + 3], iv.w, a3);
    }
    s_part[rl * 4 + q] = (a0 + a1) + (a2 + a3);
    bar_lds();                                        // B1: partials ready

    const size_t slot = ((size_t)(t & 1) * B_) * DR_;

    if (q == 0) {
      // ---- pointwise update; publish FIRST (remote critical path) ----
      float4 p  = *(const float4*)(s_part + rl * 4);
      float tot = (p.x + p.y) + (p.z + p.w) + bxj;
      float f   = retanh_f(tot);
      rj = rj + 0.1f * (f + brv_c - rj);              // a = DT/TAU
      if (t + 1 < T_) {
        union { float f; unsigned u; } cv; cv.f = rj;
        const unsigned tag = (nonce << 10) | (unsigned)(t + 1);
        unsigned long long pkt =
            ((unsigned long long)tag << 32) | (unsigned long long)cv.u;
        if (fastp) {
          pub_l2_u64(&rglobB[slot + ex_base + row], pkt);        // L2 swap only
        } else {
          __hip_atomic_store(&rglobA[slot + ex_base + row], pkt, // MALL (R1)
                             __ATOMIC_RELAXED, __HIP_MEMORY_SCOPE_AGENT);
        }
      }
      s_r[row] = rj;
      if (t + 1 < T_) s_in[rl] = inv_c;               // stage next input
      IO<BF16>::st(rstore, base_r + (size_t)t * DR_ + row, rj);
      brv_c = brv_n; inv_c = inv_n;
    } else if (t + 1 < T_) {
      // ---- poll own remote packet until tag matches ----
      const unsigned want = (nonce << 10) | (unsigned)(t + 1);
      unsigned long long v = 0;
      if (fastp) {
        const unsigned long long* aF = &rglobB[slot + ex_base + g];
        if (ok) {
          int spins = 300000;
          for (;;) {
            v = poll_l2_u64(aF);
            if ((unsigned)(v >> 32) == want) break;
            if (--spins == 0) { ok = false; break; }
          }
        } else {
          v = poll_l2_u64(aF);
        }
      } else {
        const unsigned long long* aS = &rglobA[slot + ex_base + g];
        if (ok) {
          int spins = 200000;
          for (;;) {
            v = __hip_atomic_load(aS, __ATOMIC_RELAXED, __HIP_MEMORY_SCOPE_AGENT);
            if ((unsigned)(v >> 32) == want) break;
            __builtin_amdgcn_s_sleep(1);
            if (--spins == 0) { ok = false; break; }
          }
        } else {
          v = __hip_atomic_load(aS, __ATOMIC_RELAXED, __HIP_MEMORY_SCOPE_AGENT);
        }
      }
      union { unsigned u; float f; } cv; cv.u = (unsigned)v;
      s_r[g] = cv.f;
    }
    bar_lds();                                        // B2: s_r(t), s_in(t+1) ready
  }
}

// ---------- output projection: y = rstore @ Wyr^T + by ----------
template<int BF16>
__global__ __launch_bounds__(256)
void ygemm(const void* __restrict__ Wyr,     // [DO,DR]
           const void* __restrict__ by,      // [DO]
           const void* __restrict__ rstore,  // [B*T, DR]
           void* __restrict__ y,             // [B*T, DO]
           const int* __restrict__ flag)
{
  if (*flag != BF16) return;
  const int tid  = threadIdx.x;
  const int wave = tid >> 6;
  const int lane = tid & 63;
  const int base = blockIdx.x * 64;          // first row of this block

  __shared__ __align__(16) float rs_c[64 * 128];        // 32 KB
  __shared__ __align__(16) float wy_c[64 * 132];        // 33.8 KB (pad vs bank hits)

  float acc[16];
  #pragma unroll
  for (int i = 0; i < 16; ++i) acc[i] = 0.f;

  #pragma unroll 1
  for (int kc = 0; kc < 4; ++kc) {
    for (int n = tid; n < 8192; n += 256) {
      int r = n >> 7, k = n & 127;
      rs_c[r * 128 + k] = IO<BF16>::ld(rstore, (size_t)(base + r) * DR_ + kc * 128 + k);
    }
    for (int n = tid; n < 8192; n += 256) {
      int o = n >> 7, k = n & 127;
      wy_c[o * 132 + k] = IO<BF16>::ld(Wyr, (size_t)o * DR_ + kc * 128 + k);
    }
    __syncthreads();

    float4 wf[32];
    #pragma unroll
    for (int m = 0; m < 32; ++m)
      wf[m] = *(const float4*)(wy_c + lane * 132 + m * 4);

    #pragma unroll 1
    for (int i = 0; i < 16; ++i) {
      int r = wave * 16 + i;
      float s0 = 0.f, s1 = 0.f, s2 = 0.f, s3 = 0.f;
      #pragma unroll
      for (int m = 0; m < 32; ++m) {
        float4 rv = *(const float4*)(rs_c + r * 128 + m * 4);   // broadcast
        s0 = fmaf(wf[m].x, rv.x, s0);
        s1 = fmaf(wf[m].y, rv.y, s1);
        s2 = fmaf(wf[m].z, rv.z, s2);
        s3 = fmaf(wf[m].w, rv.w, s3);
      }
      acc[i] += (s0 + s1) + (s2 + s3);
    }
    __syncthreads();
  }

  const float byl = IO<BF16>::ld(by, lane);
  #pragma unroll
  for (int i = 0; i < 16; ++i) {
    int r = base + wave * 16 + i;
    IO<BF16>::st(y, (size_t)r * DO_ + lane, acc[i] + byl);
  }
}

extern "C" void kernel_launch(void* const* d_in, const int* in_sizes, int n_in,
                              void* d_out, int out_size, void* d_ws, size_t ws_size,
                              hipStream_t stream) {
  const void* inp = d_in[0];
  const void* brn = d_in[1];
  const void* Wrx = d_in[2];
  const void* bx  = d_in[3];
  const void* Wrr = d_in[4];
  const void* Wyr = d_in[5];
  const void* by  = d_in[6];
  const void* r0  = d_in[7];

  // workspace: [0] flag | [64] nonce | [256] det[256] u32 | [2048] probe[256] u64
  //            [4096] rglobA [2][B][DR] u64 | [+512KB] rglobB same
  char* ws = (char*)d_ws;
  int*                flag   = (int*)ws;
  unsigned*           nonce  = (unsigned*)(ws + 64);
  unsigned*           det    = (unsigned*)(ws + 256);
  unsigned long long* probe  = (unsigned long long*)(ws + 2048);
  unsigned long long* rglobA = (unsigned long long*)(ws + 4096);
  unsigned long long* rglobB = rglobA + (size_t)2 * B_ * DR_;

  uint16_t* y_bf  = (uint16_t*)d_out;
  uint16_t* rs_bf = y_bf + (size_t)B_ * T_ * DO_;
  float*    y_f   = (float*)d_out;
  float*    rs_f  = y_f + (size_t)B_ * T_ * DO_;

  hipLaunchKernelGGL(init_kernel, dim3(512), dim3(256), 0, stream,
                     (const uint16_t*)bx, flag, nonce, det, probe, rglobA);

  hipLaunchKernelGGL((rnn_run<1>), dim3(4 * B_), dim3(512), 0, stream,
                     inp, brn, Wrx, bx, Wrr, r0, (void*)rs_bf, flag,
                     nonce, det, probe, rglobA, rglobB);
  hipLaunchKernelGGL((rnn_run<0>), dim3(4 * B_), dim3(512), 0, stream,
                     inp, brn, Wrx, bx, Wrr, r0, (void*)rs_f, flag,
                     nonce, det, probe, rglobA, rglobB);

  hipLaunchKernelGGL((ygemm<1>), dim3((B_ * T_) / 64), dim3(256), 0, stream,
                     Wyr, by, (const void*)rs_bf, (void*)y_bf, flag);
  hipLaunchKernelGGL((ygemm<0>), dim3((B_ * T_) / 64), dim3(256), 0, stream,
                     Wyr, by, (const void*)rs_f, (void*)y_f, flag);
}